// Round 14
// baseline (290.520 us; speedup 1.0000x reference)
//
#include <hip/hip_runtime.h>
#include <hip/hip_fp16.h>

#define NN  25000
#define EE  500000
#define BB  4
#define DD  32
#define LL  4
#define R2C 474
#define BD  128      // B*D
#define THD 416      // 13*D
#define EPSF 1e-6f
#define WMH 13312    // halfs per layer of MFMA-packed W: 13 t * 2 nt * 64 * 8

typedef _Float16 half8 __attribute__((ext_vector_type(8)));
typedef _Float16 h2v   __attribute__((ext_vector_type(2)));
typedef float    f32x4 __attribute__((ext_vector_type(4)));
typedef float    f2v   __attribute__((ext_vector_type(2)));

// ---------------- graph build ----------------
// Fused count + slot assignment, 4 edges/thread (4 atomics in flight).
__global__ __launch_bounds__(256) void pidx_kernel(const int4* __restrict__ no4,
                                                   int* __restrict__ cnt,
                                                   int4* __restrict__ pidx4) {
  int i = blockIdx.x * 256 + threadIdx.x;
  if (i >= EE / 4) return;
  int4 d = no4[i];
  int4 r;
  r.x = atomicAdd(&cnt[d.x], 1);
  r.y = atomicAdd(&cnt[d.y], 1);
  r.z = atomicAdd(&cnt[d.z], 1);
  r.w = atomicAdd(&cnt[d.w], 1);
  pidx4[i] = r;
}

// Order-free CSR with EVEN-aligned segments.
__global__ __launch_bounds__(256) void prep_kernel(const int* __restrict__ cnt,
                                                   int* __restrict__ base,
                                                   int* __restrict__ gcnt) {
  int n = blockIdx.x * 256 + threadIdx.x;
  if (n >= NN) return;
  base[n] = atomicAdd(gcnt, (cnt[n] + 1) & ~1);
}

// atomic-free scatter of 8B records {node_in | rel<<15, w as replicated half2}
__global__ __launch_bounds__(256) void scatter_kernel(const int4* __restrict__ ni4,
                                                      const int4* __restrict__ no4,
                                                      const int4* __restrict__ rl4,
                                                      const float4* __restrict__ ew4,
                                                      const int* __restrict__ base,
                                                      const int4* __restrict__ pidx4,
                                                      int2* __restrict__ ep) {
  int i = blockIdx.x * 256 + threadIdx.x;
  if (i >= EE / 4) return;
  int4 ni = ni4[i], no = no4[i], rl = rl4[i], pi = pidx4[i];
  float4 w = ew4[i];
  h2v wa = {(_Float16)w.x, (_Float16)w.x};
  h2v wb = {(_Float16)w.y, (_Float16)w.y};
  h2v wc = {(_Float16)w.z, (_Float16)w.z};
  h2v wd = {(_Float16)w.w, (_Float16)w.w};
  ep[base[no.x] + pi.x] = make_int2(ni.x | (rl.x << 15), *(int*)&wa);
  ep[base[no.y] + pi.y] = make_int2(ni.y | (rl.y << 15), *(int*)&wb);
  ep[base[no.z] + pi.z] = make_int2(ni.z | (rl.z << 15), *(int*)&wc);
  ep[base[no.w] + pi.w] = make_int2(ni.w | (rl.w << 15), *(int*)&wd);
}

// per-node weighted degree from packed segments; block-reduced logsum.
__global__ __launch_bounds__(256) void wdeg_kernel(const int* __restrict__ base,
                                                   const int* __restrict__ cnt,
                                                   const int2* __restrict__ ep,
                                                   float* __restrict__ lg,
                                                   float* __restrict__ logsum) {
  int n = blockIdx.x * 256 + threadIdx.x;
  float v = 0.f;
  if (n < NN) {
    int b = base[n], c = cnt[n];
    float s = 0.f;
    for (int p = b; p < b + c; ++p) {
      int wi = ep[p].y;
      h2v wh = *reinterpret_cast<h2v*>(&wi);
      s += (float)wh.x;
    }
    v = logf(s + 1.0f);
    lg[n] = v;
  }
  __shared__ float red[256];
  red[threadIdx.x] = v; __syncthreads();
  for (int o = 128; o > 0; o >>= 1) {
    if (threadIdx.x < o) red[threadIdx.x] += red[threadIdx.x + o];
    __syncthreads();
  }
  if (threadIdx.x == 0) atomicAdd(logsum, red[0]);
}

// Pack lin_W into MFMA B-fragment order (fp16); block 0 also builds query.
__global__ __launch_bounds__(256) void wmbuild_kernel(const float* __restrict__ linW,
                                                      const int* __restrict__ r_index,
                                                      const float* __restrict__ qemb,
                                                      float* __restrict__ query,
                                                      _Float16* __restrict__ Wm) {
  if (blockIdx.x == 0 && threadIdx.x < 128) {
    int t = threadIdx.x; int b = t >> 5, d = t & 31;
    query[t] = qemb[r_index[b] * DD + d];
  }
  int idx = blockIdx.x * 256 + threadIdx.x;
  if (idx >= LL * WMH) return;
  int l = idx / WMH, rest = idx % WMH;
  int t = rest >> 10;
  int nt = (rest >> 9) & 1;
  int L = (rest >> 3) & 63;
  int j = rest & 7;
  int k = t * 32 + (L >> 4) * 8 + j;
  int n = nt * 16 + (L & 15);
  int wrow;
  if (k < 32) wrow = k;
  else {
    int kk = k - 32;
    int slab = kk >> 7, s = (kk >> 5) & 3, dd = kk & 31;
    wrow = DD + (dd * 4 + s) * 3 + slab;
  }
  Wm[idx] = (_Float16)linW[(size_t)l * THD * DD + (size_t)wrow * DD + n];
}

// rel_in for ALL layers upfront (depends only on query, not hidden)
__global__ __launch_bounds__(256) void relin_all_kernel(const float* __restrict__ query,
                                                        const float* __restrict__ relW,
                                                        const float* __restrict__ relB,
                                                        __half* __restrict__ relIn) {
  int o = blockIdx.x * 256 + threadIdx.x;
  if (o >= LL * R2C * BD) return;
  int l = o / (R2C * BD);
  int rest = o % (R2C * BD);
  int r = rest >> 7, b = (rest >> 5) & 3, d = rest & 31;
  int col = r * DD + d;
  const float* W = relW + (size_t)l * DD * R2C * DD;
  float acc = relB[(size_t)l * R2C * DD + col];
  #pragma unroll
  for (int k = 0; k < DD; ++k)
    acc = fmaf(query[b * DD + k], W[(size_t)k * (R2C * DD) + col], acc);
  relIn[o] = __float2half(acc);
}

// ---- shared MFMA epilogue: one wave computes 16x32 linear for 4 nodes ----
__device__ __forceinline__ void mfma_epilogue(const _Float16* sh,
                                              const _Float16* hinh,
                                              __half* houth,
                                              const float* lg,
                                              const float* logsum,
                                              const _Float16* Wm,
                                              const float* bias,
                                              const float* query,
                                              const int* h_index,
                                              int nbase, int lane, bool hzero) {
  const int m = lane & 15;
  const int q = lane >> 4;
  const int nl = m >> 2;
  const int n = nbase + nl;
  const int b = m & 3;
  const float sc = lg[n] * ((float)NN / logsum[0]);
  const _Float16 one = (_Float16)1.f;
  const _Float16 s1h = (_Float16)sc;
  const _Float16 s2h = (_Float16)(1.0f / fmaxf(sc, 0.01f));
  const _Float16* ssrc = sh + nl * 512 + b * 32 + q * 8;

  f32x4 c0 = {0.f, 0.f, 0.f, 0.f};
  f32x4 c1 = {0.f, 0.f, 0.f, 0.f};
  half8 a;
  if (hzero) {
    a = (half8)(_Float16)0.f;
    if (n == h_index[b]) {
      const float* qp = query + b * 32 + q * 8;
      #pragma unroll
      for (int j = 0; j < 8; ++j) a[j] = (_Float16)qp[j];
    }
  } else {
    a = *(const half8*)(hinh + (unsigned)n * BD + b * 32 + q * 8);
  }
  #pragma unroll
  for (int t = 0; t < 13; ++t) {
    if (t > 0) {
      const int slab = (t - 1) >> 2, s = (t - 1) & 3;
      a = *(const half8*)(ssrc + s * 128);
      const _Float16 sch = (slab == 0) ? one : ((slab == 1) ? s1h : s2h);
      half8 sv = {sch, sch, sch, sch, sch, sch, sch, sch};
      a = a * sv;
    }
    half8 b0 = *(const half8*)(Wm + (unsigned)(t * 2 + 0) * 512 + lane * 8);
    half8 b1 = *(const half8*)(Wm + (unsigned)(t * 2 + 1) * 512 + lane * 8);
    c0 = __builtin_amdgcn_mfma_f32_16x16x32_f16(a, b0, c0, 0, 0, 0);
    c1 = __builtin_amdgcn_mfma_f32_16x16x32_f16(a, b1, c1, 0, 0, 0);
  }
  const int col = lane & 15;
  const float bj0 = bias[col], bj1 = bias[col + 16];
  #pragma unroll
  for (int i = 0; i < 4; ++i) {
    const int mr = q * 4 + i;
    __half* dst = houth + (unsigned)(nbase + (mr >> 2)) * BD + (mr & 3) * 32 + col;
    dst[0]  = __float2half(fmaxf(c0[i] + bj0, 0.f));
    dst[16] = __float2half(fmaxf(c1[i] + bj1, 0.f));
  }
}

// ---------------- fused layer 1: analytic sparse gather + MFMA linear ------
__global__ __launch_bounds__(256) void layer1_fused_kernel(
    const h2v* __restrict__ rel2, const int2* __restrict__ ep,
    const int* __restrict__ base, const int* __restrict__ cnt,
    const int* __restrict__ h_index, const float* __restrict__ query,
    const float* __restrict__ lg, const float* __restrict__ logsum,
    const _Float16* __restrict__ Wm, const float* __restrict__ bias,
    __half* __restrict__ houth) {
  __shared__ __align__(16) h2v sh[4][256];   // [wave][s*64 + lane]
  const int lane = threadIdx.x & 63;
  const int wid  = threadIdx.x >> 6;
  const int nbase = blockIdx.x * 4;
  const int n = nbase + wid;
  const int b = lane >> 4;
  const int d0 = (lane & 15) * 2;
  const float q0 = query[b * 32 + d0], q1 = query[b * 32 + d0 + 1];
  const int hb = h_index[b];
  const int beg = __builtin_amdgcn_readfirstlane(base[n]);
  const int cnn = __builtin_amdgcn_readfirstlane(cnt[n]);
  const float mb0 = (n == hb) ? q0 : 0.f;
  const float mb1 = (n == hb) ? q1 : 0.f;
  float sa0 = mb0, qa0 = mb0 * mb0, mx0 = mb0, mn0 = mb0;
  float sa1 = mb1, qa1 = mb1 * mb1, mx1 = mb1, mn1 = mb1;
  int matched = 0;
  for (int p = beg; p < beg + cnn; ++p) {
    int2 e = ep[p];
    if ((e.x & 0x7fff) == hb) {
      h2v rv = rel2[(unsigned)((unsigned)e.x >> 15) * 64 + lane];
      int wi = e.y;
      h2v wh = *reinterpret_cast<h2v*>(&wi);
      float w = (float)wh.x;
      float m0 = (float)rv.x * q0, mw0 = m0 * w;
      float m1 = (float)rv.y * q1, mw1 = m1 * w;
      sa0 += mw0; qa0 = fmaf(m0, mw0, qa0); mx0 = fmaxf(mx0, mw0); mn0 = fminf(mn0, mw0);
      sa1 += mw1; qa1 = fmaf(m1, mw1, qa1); mx1 = fmaxf(mx1, mw1); mn1 = fminf(mn1, mw1);
      ++matched;
    }
  }
  if (matched < cnn) {
    mx0 = fmaxf(mx0, 0.f); mn0 = fminf(mn0, 0.f);
    mx1 = fmaxf(mx1, 0.f); mn1 = fminf(mn1, 0.f);
  }
  const float invc = 1.0f / (float)(cnn + 1);
  const float mean0 = sa0 * invc, mean1 = sa1 * invc;
  const float sd0 = sqrtf(fmaxf(qa0 * invc - mean0 * mean0, EPSF));
  const float sd1 = sqrtf(fmaxf(qa1 * invc - mean1 * mean1, EPSF));
  sh[wid][lane]       = (h2v){(_Float16)mean0, (_Float16)mean1};
  sh[wid][64 + lane]  = (h2v){(_Float16)mx0, (_Float16)mx1};
  sh[wid][128 + lane] = (h2v){(_Float16)mn0, (_Float16)mn1};
  sh[wid][192 + lane] = (h2v){(_Float16)sd0, (_Float16)sd1};
  __syncthreads();
  if (threadIdx.x >= 64) return;
  mfma_epilogue((const _Float16*)&sh[0][0], nullptr, houth, lg, logsum,
                Wm, bias, query, h_index, nbase, lane, true);
}

// ---------------- fused generic layer: gather + MFMA linear ----------------
// Packed-fp16 message math: v_pk_mul for m and mw, v_pk_max/min for extrema;
// sum and sum-of-squares accumulate in fp32.
__global__ __launch_bounds__(256) void layer_fused_kernel(
    const h2v* __restrict__ hin2, const h2v* __restrict__ rel2,
    const int2* __restrict__ ep, const int* __restrict__ base,
    const int* __restrict__ cnt, const int* __restrict__ h_index,
    const float* __restrict__ query, const float* __restrict__ lg,
    const float* __restrict__ logsum, const _Float16* __restrict__ Wm,
    const float* __restrict__ bias, __half* __restrict__ houth) {
  __shared__ __align__(16) h2v sh[4][256];
  const int lane = threadIdx.x & 63;
  const int wid  = threadIdx.x >> 6;
  const int nbase = blockIdx.x * 4;
  const int n = nbase + wid;
  const int b = lane >> 4;
  const int d0 = (lane & 15) * 2;
  const float q0 = query[b * 32 + d0], q1 = query[b * 32 + d0 + 1];
  const int hb = h_index[b];
  const int beg = __builtin_amdgcn_readfirstlane(base[n]);
  const int cnn = __builtin_amdgcn_readfirstlane(cnt[n]);
  const float mb0 = (n == hb) ? q0 : 0.f;
  const float mb1 = (n == hb) ? q1 : 0.f;
  float sa0 = mb0, qa0 = mb0 * mb0;
  float sa1 = mb1, qa1 = mb1 * mb1;
  h2v mx2 = {(_Float16)mb0, (_Float16)mb1};
  h2v mn2 = mx2;

#define PROC(EwInt, Hv, Rv) {                                                \
    int _wi = (EwInt);                                                       \
    h2v _wh = *reinterpret_cast<h2v*>(&_wi);                                 \
    h2v _mh = (Hv) * (Rv);                                                   \
    h2v _mwh = _mh * _wh;                                                    \
    mx2 = __builtin_elementwise_max(mx2, _mwh);                              \
    mn2 = __builtin_elementwise_min(mn2, _mwh);                              \
    f2v _mf = __builtin_convertvector(_mh, f2v);                             \
    f2v _mwf = __builtin_convertvector(_mwh, f2v);                           \
    sa0 += _mwf.x; sa1 += _mwf.y;                                            \
    qa0 = fmaf(_mf.x, _mwf.x, qa0); qa1 = fmaf(_mf.y, _mwf.y, qa1); }
#define ROWS(Ex, Hd, Rd) {                                                   \
    Hd = hin2[(unsigned)((Ex) & 0x7fff) * 64 + lane];                        \
    Rd = rel2[(unsigned)((unsigned)(Ex) >> 15) * 64 + lane]; }

  int p = beg;
  int rem = cnn;
  const int nb = rem >> 3;
  if (nb > 0) {
    int2 E0, E1, E2, E3, E4, E5, E6, E7;
    h2v H0, H1, H2, H3, H4, H5, H6, H7;
    h2v R0, R1, R2, R3, R4, R5, R6, R7;
    E0 = ep[p];     E1 = ep[p + 1]; E2 = ep[p + 2]; E3 = ep[p + 3];
    E4 = ep[p + 4]; E5 = ep[p + 5]; E6 = ep[p + 6]; E7 = ep[p + 7];
    ROWS(E0.x, H0, R0); ROWS(E1.x, H1, R1); ROWS(E2.x, H2, R2); ROWS(E3.x, H3, R3);
    ROWS(E4.x, H4, R4); ROWS(E5.x, H5, R5); ROWS(E6.x, H6, R6); ROWS(E7.x, H7, R7);
    for (int it = 1; it < nb; ++it) {
      const int pn = p + 8;
      int2 F0 = ep[pn],     F1 = ep[pn + 1], F2 = ep[pn + 2], F3 = ep[pn + 3];
      int2 F4 = ep[pn + 4], F5 = ep[pn + 5], F6 = ep[pn + 6], F7 = ep[pn + 7];
      h2v G0, G1, G2, G3, G4, G5, G6, G7;
      h2v S0, S1, S2, S3, S4, S5, S6, S7;
      ROWS(F0.x, G0, S0); ROWS(F1.x, G1, S1); ROWS(F2.x, G2, S2); ROWS(F3.x, G3, S3);
      ROWS(F4.x, G4, S4); ROWS(F5.x, G5, S5); ROWS(F6.x, G6, S6); ROWS(F7.x, G7, S7);
      PROC(E0.y, H0, R0); PROC(E1.y, H1, R1); PROC(E2.y, H2, R2); PROC(E3.y, H3, R3);
      PROC(E4.y, H4, R4); PROC(E5.y, H5, R5); PROC(E6.y, H6, R6); PROC(E7.y, H7, R7);
      E0 = F0; E1 = F1; E2 = F2; E3 = F3; E4 = F4; E5 = F5; E6 = F6; E7 = F7;
      H0 = G0; H1 = G1; H2 = G2; H3 = G3; H4 = G4; H5 = G5; H6 = G6; H7 = G7;
      R0 = S0; R1 = S1; R2 = S2; R3 = S3; R4 = S4; R5 = S5; R6 = S6; R7 = S7;
      p = pn;
    }
    PROC(E0.y, H0, R0); PROC(E1.y, H1, R1); PROC(E2.y, H2, R2); PROC(E3.y, H3, R3);
    PROC(E4.y, H4, R4); PROC(E5.y, H5, R5); PROC(E6.y, H6, R6); PROC(E7.y, H7, R7);
    p += 8;
    rem -= nb << 3;
  }
  if (rem >= 4) {
    int2 E0 = ep[p], E1 = ep[p + 1], E2 = ep[p + 2], E3 = ep[p + 3];
    h2v H0, H1, H2, H3, R0, R1, R2, R3;
    ROWS(E0.x, H0, R0); ROWS(E1.x, H1, R1); ROWS(E2.x, H2, R2); ROWS(E3.x, H3, R3);
    PROC(E0.y, H0, R0); PROC(E1.y, H1, R1); PROC(E2.y, H2, R2); PROC(E3.y, H3, R3);
    p += 4; rem -= 4;
  }
  for (; rem > 0; --rem, ++p) {
    int2 e = ep[p];
    h2v hv, rv;
    ROWS(e.x, hv, rv);
    PROC(e.y, hv, rv);
  }
#undef ROWS
#undef PROC
  const float invc = 1.0f / (float)(cnn + 1);
  const float mean0 = sa0 * invc, mean1 = sa1 * invc;
  const float sd0 = sqrtf(fmaxf(qa0 * invc - mean0 * mean0, EPSF));
  const float sd1 = sqrtf(fmaxf(qa1 * invc - mean1 * mean1, EPSF));
  sh[wid][lane]       = (h2v){(_Float16)mean0, (_Float16)mean1};
  sh[wid][64 + lane]  = mx2;
  sh[wid][128 + lane] = mn2;
  sh[wid][192 + lane] = (h2v){(_Float16)sd0, (_Float16)sd1};
  __syncthreads();
  if (threadIdx.x >= 64) return;
  mfma_epilogue((const _Float16*)&sh[0][0], (const _Float16*)hin2, houth,
                lg, logsum, Wm, bias, query, h_index, nbase, lane, false);
}

// final MLP: [hidden(fp16), query] (64) -> relu(64) -> 1, out[b*N + n]
__global__ __launch_bounds__(128) void mlp_kernel(const __half* __restrict__ hinh,
                                                  const float* __restrict__ query,
                                                  const float* __restrict__ W1,
                                                  const float* __restrict__ b1,
                                                  const float* __restrict__ W2,
                                                  const float* __restrict__ b2,
                                                  float* __restrict__ out) {
  __shared__ float f2[BB][2 * DD];
  const int t = threadIdx.x;
  const int b = t >> 5, d = t & 31;
  const float qv = query[t];
  const float w2a = W2[d], w2b = W2[DD + d];
  const float b1a = b1[d], b1b = b1[DD + d];
  const float b2v = b2[0];
  const int NPBM = 8;
  int n0 = blockIdx.x * NPBM, n1 = min(n0 + NPBM, NN);
  for (int n = n0; n < n1; ++n) {
    f2[b][d]      = __half2float(hinh[(unsigned)n * BD + t]);
    f2[b][DD + d] = qv;
    float a0 = b1a, a1 = b1b;
    #pragma unroll
    for (int i = 0; i < 2 * DD; ++i) {
      float v = f2[b][i];
      a0 = fmaf(v, W1[i * 2 * DD + d], a0);
      a1 = fmaf(v, W1[i * 2 * DD + DD + d], a1);
    }
    a0 = fmaxf(a0, 0.f); a1 = fmaxf(a1, 0.f);
    float part = a0 * w2a + a1 * w2b;
    #pragma unroll
    for (int off = 16; off > 0; off >>= 1) part += __shfl_down(part, off, 32);
    if (d == 0) out[b * NN + n] = part + b2v;
  }
}

extern "C" void kernel_launch(void* const* d_in, const int* in_sizes, int n_in,
                              void* d_out, int out_size, void* d_ws, size_t ws_size,
                              hipStream_t stream) {
  const int*   node_in  = (const int*)d_in[0];
  const int*   node_out = (const int*)d_in[1];
  const int*   relation = (const int*)d_in[2];
  const float* ew       = (const float*)d_in[3];
  const int*   h_index  = (const int*)d_in[4];
  const int*   r_index  = (const int*)d_in[5];
  const float* qemb     = (const float*)d_in[6];
  const float* relW     = (const float*)d_in[7];
  const float* relB     = (const float*)d_in[8];
  const float* linW     = (const float*)d_in[9];
  const float* linB     = (const float*)d_in[10];
  const float* W1       = (const float*)d_in[11];
  const float* b1       = (const float*)d_in[12];
  const float* W2       = (const float*)d_in[13];
  const float* b2       = (const float*)d_in[14];
  float* out = (float*)d_out;

  char* ws = (char*)d_ws;
  size_t off = 0;
  auto alloc = [&](size_t bytes) -> char* {
    char* p = ws + off;
    off += (bytes + 255) & ~(size_t)255;
    return p;
  };
  __half*   h0     = (__half*)  alloc((size_t)NN * BD * 2);
  __half*   h1     = (__half*)  alloc((size_t)NN * BD * 2);
  __half*   relIn  = (__half*)  alloc((size_t)LL * R2C * BD * 2);
  _Float16* Wm     = (_Float16*)alloc((size_t)LL * WMH * 2);
  int2*     ep     = (int2*)    alloc(((size_t)EE + NN) * 8);  // even-aligned segs
  int*      pidx   = (int*)     alloc((size_t)EE * 4);
  int*      base   = (int*)     alloc((size_t)NN * 4);
  int*      cnti   = (int*)     alloc((size_t)NN * 4);
  float*    lg     = (float*)   alloc((size_t)NN * 4);
  float*    query  = (float*)   alloc((size_t)BD * 4);
  float*    stats  = (float*)   alloc(256);   // [0]=logsum (f32), [1]=gcnt (int)

  hipMemsetAsync(cnti, 0, (size_t)NN * 4, stream);
  hipMemsetAsync(stats, 0, 256, stream);

  float* logsum = stats;
  int*   gcnt   = (int*)stats + 1;

  pidx_kernel   <<<(EE / 4 + 255) / 256, 256, 0, stream>>>((const int4*)node_out,
                                                           cnti, (int4*)pidx);
  prep_kernel   <<<(NN + 255) / 256, 256, 0, stream>>>(cnti, base, gcnt);
  scatter_kernel<<<(EE / 4 + 255) / 256, 256, 0, stream>>>(
      (const int4*)node_in, (const int4*)node_out, (const int4*)relation,
      (const float4*)ew, base, (const int4*)pidx, ep);
  wdeg_kernel   <<<(NN + 255) / 256, 256, 0, stream>>>(base, cnti, ep, lg, logsum);
  wmbuild_kernel<<<(LL * WMH + 255) / 256, 256, 0, stream>>>(linW, r_index, qemb,
                                                             query, Wm);
  relin_all_kernel<<<(LL * R2C * BD + 255) / 256, 256, 0, stream>>>(query, relW, relB, relIn);

  __half* hin = h0; __half* hout = h1;
  for (int l = 0; l < LL; ++l) {
    if (l == 0) {
      layer1_fused_kernel<<<NN / 4, 256, 0, stream>>>(
          (const h2v*)relIn, ep, base, cnti, h_index, query, lg, logsum,
          Wm, linB, hout);
    } else {
      layer_fused_kernel<<<NN / 4, 256, 0, stream>>>(
          (const h2v*)hin, (const h2v*)relIn + (size_t)l * R2C * 64,
          ep, base, cnti, h_index, query, lg, logsum,
          Wm + (size_t)l * WMH, linB + (size_t)l * DD, hout);
    }
    __half* tmp = hin; hin = hout; hout = tmp;
  }
  mlp_kernel<<<(NN + 7) / 8, 128, 0, stream>>>(hin, query, W1, b1, W2, b2, out);
}